// Round 3
// baseline (760.319 us; speedup 1.0000x reference)
//
#include <hip/hip_runtime.h>
#include <hip/hip_bf16.h>
#include <math.h>

// Problem constants (fixed by setup_inputs)
constexpr int kB  = 4;
constexpr int kH  = 128;
constexpr int kW  = 128;
constexpr int kHW = kH * kW;          // 16384
constexpr int kC1 = 256;              // layer1 in channels
constexpr int kM  = 128;              // mid channels
constexpr int kC2 = 256;              // layer2 out channels

typedef unsigned short u16;
typedef __attribute__((ext_vector_type(8))) short bf16x8;
typedef __attribute__((ext_vector_type(4))) float f32x4;

__device__ inline float bf2f(short s) {
  return __uint_as_float(((unsigned)(u16)s) << 16);
}
__device__ inline u16 f2bf(float f) {
  unsigned u = __float_as_uint(f);
  unsigned r = u + 0x7FFFu + ((u >> 16) & 1u);
  return (u16)(r >> 16);
}

// ---------------- NCHW f32 -> NHWC bf16 (optionally fused BN+ReLU) ----------
template <bool BN>
__global__ __launch_bounds__(256) void to_nhwc(const float* __restrict__ src,
                                               const float* __restrict__ ss,
                                               u16* __restrict__ dst, int C) {
  int pxg = blockIdx.x * 256 + threadIdx.x;  // 0 .. B*HW-1
  int b = pxg >> 14, p = pxg & 16383;
  const float* sp = src + (size_t)b * C * kHW + p;
  u16* dp = dst + (size_t)pxg * C;
  for (int c = 0; c < C; c += 2) {
    float v0 = sp[(size_t)c * kHW], v1 = sp[(size_t)(c + 1) * kHW];
    if (BN) {
      v0 = fmaxf(fmaf(v0, ss[2 * c], ss[2 * c + 1]), 0.f);
      v1 = fmaxf(fmaf(v1, ss[2 * c + 2], ss[2 * c + 3]), 0.f);
    }
    unsigned pk = (unsigned)f2bf(v0) | ((unsigned)f2bf(v1) << 16);
    *(unsigned*)(dp + c) = pk;
  }
}

// ------------- weight pre-pack into MFMA B-fragment order -------------------
// layout: [9][CIN/32][NTOT][64 lanes][8] ; k_local = 8*(lane>>4)+j -> channel,
// n = 16*nt + (lane&15)
__global__ __launch_bounds__(256) void prep_bpack(const float* __restrict__ w,
                                                  u16* __restrict__ bp, int CIN,
                                                  int ntiles, int OREAL) {
  int i = blockIdx.x * 256 + threadIdx.x;
  int total = 9 * (CIN / 32) * ntiles * 512;
  if (i >= total) return;
  int j = i & 7, l = (i >> 3) & 63;
  int rest = i >> 9;
  int nt = rest % ntiles; rest /= ntiles;
  int ch = rest % (CIN / 32);
  int tap = rest / (CIN / 32);
  int c = ch * 32 + ((l >> 4) << 3) + j;
  int o = nt * 16 + (l & 15);
  float v = (o < OREAL) ? w[((size_t)o * CIN + c) * 9 + tap] : 0.f;
  bp[i] = f2bf(v);
}

// ---------------- fused (deformable) conv via MFMA implicit GEMM ------------
// Block: 64 pixels (8x8 tile) x NT*16 outputs; 4 waves split M (16 px each).
// A-fragments built directly in registers (gather+blend); B streamed from
// prepacked global. No LDS, no barriers.
template <int CIN, int NTOT, int NT, int OREAL, bool DEFORM>
__global__ __launch_bounds__(256, 4) void dcn_mfma(
    const u16* __restrict__ xt, const float* __restrict__ om,
    const float* __restrict__ boff, const u16* __restrict__ bpack,
    const float* __restrict__ bias, float* __restrict__ y) {
  constexpr int NCH = CIN / 32;
  const int tid = threadIdx.x;
  const int lane = tid & 63;
  const int wv = tid >> 6;
  const int tile = blockIdx.x, b = blockIdx.y;
  const int h0 = (tile >> 4) << 3, w0 = (tile & 15) << 3;
  const int px = (wv << 4) + (lane & 15);  // wave's pixel (M-row)
  const int h = h0 + (px >> 3), w = w0 + (px & 7);
  const int cg = lane >> 4;                // channel sub-group (k_local/8)
  const u16* xb = xt + (size_t)b * kHW * CIN;

  f32x4 acc[NT];
#pragma unroll
  for (int nt = 0; nt < NT; nt++) acc[nt] = (f32x4){0.f, 0.f, 0.f, 0.f};

  for (int tap = 0; tap < 9; tap++) {
    const int dy = tap / 3 - 1, dx = tap % 3 - 1;
    int a0 = 0, a1 = 0, a2 = 0, a3 = 0;
    float g0 = 0.f, g1 = 0.f, g2 = 0.f, g3 = 0.f;
    if (DEFORM) {
      const float* omb = om + ((size_t)(b * 27 + tap)) * kHW + h * kW + w;
      float offy = omb[0] + boff[tap];
      float offx = omb[(size_t)9 * kHW] + boff[9 + tap];
      float ml = omb[(size_t)18 * kHW] + boff[18 + tap];
      float mask = 1.f / (1.f + expf(-ml));
      float py = (float)(h + dy) + offy;
      float qx = (float)(w + dx) + offx;
      float fy = floorf(py), fx = floorf(qx);
      float ly = py - fy, lx = qx - fx;
      int yi = (int)fy, xi = (int)fx;
      bool vy0 = (yi >= 0) & (yi < kH), vy1 = (yi + 1 >= 0) & (yi + 1 < kH);
      bool vx0 = (xi >= 0) & (xi < kW), vx1 = (xi + 1 >= 0) & (xi + 1 < kW);
      int y0c = min(max(yi, 0), kH - 1), y1c = min(max(yi + 1, 0), kH - 1);
      int x0c = min(max(xi, 0), kW - 1), x1c = min(max(xi + 1, 0), kW - 1);
      a0 = (y0c * kW + x0c) * CIN;
      a1 = (y0c * kW + x1c) * CIN;
      a2 = (y1c * kW + x0c) * CIN;
      a3 = (y1c * kW + x1c) * CIN;
      g0 = (vy0 && vx0) ? (1.f - ly) * (1.f - lx) * mask : 0.f;
      g1 = (vy0 && vx1) ? (1.f - ly) * lx * mask : 0.f;
      g2 = (vy1 && vx0) ? ly * (1.f - lx) * mask : 0.f;
      g3 = (vy1 && vx1) ? ly * lx * mask : 0.f;
    } else {
      int yy = h + dy, xx = w + dx;
      bool v = (yy >= 0) && (yy < kH) && (xx >= 0) && (xx < kW);
      a0 = v ? (yy * kW + xx) * CIN : 0;
      g0 = v ? 1.f : 0.f;
    }

    for (int ch = 0; ch < NCH; ch++) {
      const int coff = ch * 32 + cg * 8;
      bf16x8 af;
      if (DEFORM) {
        bf16x8 v0 = *reinterpret_cast<const bf16x8*>(xb + a0 + coff);
        bf16x8 v1 = *reinterpret_cast<const bf16x8*>(xb + a1 + coff);
        bf16x8 v2 = *reinterpret_cast<const bf16x8*>(xb + a2 + coff);
        bf16x8 v3 = *reinterpret_cast<const bf16x8*>(xb + a3 + coff);
#pragma unroll
        for (int j = 0; j < 8; j++) {
          float s = g0 * bf2f(v0[j]);
          s = fmaf(g1, bf2f(v1[j]), s);
          s = fmaf(g2, bf2f(v2[j]), s);
          s = fmaf(g3, bf2f(v3[j]), s);
          af[j] = (short)f2bf(s);
        }
      } else {
        af = (bf16x8){0, 0, 0, 0, 0, 0, 0, 0};
        if (g0 != 0.f) af = *reinterpret_cast<const bf16x8*>(xb + a0 + coff);
      }
      const u16* bp = bpack +
                      (((size_t)tap * NCH + ch) * NTOT + blockIdx.z * NT) * 512 +
                      (size_t)lane * 8;
#pragma unroll
      for (int nt = 0; nt < NT; nt++) {
        bf16x8 bfr = *reinterpret_cast<const bf16x8*>(bp + nt * 512);
        acc[nt] =
            __builtin_amdgcn_mfma_f32_16x16x32_bf16(af, bfr, acc[nt], 0, 0, 0);
      }
    }
  }

  // epilogue: D layout col(n)=lane&15, row(m)=4*(lane>>4)+r within wave's frag
#pragma unroll
  for (int nt = 0; nt < NT; nt++) {
    int o = (blockIdx.z * NT + nt) * 16 + (lane & 15);
    if (OREAL < NTOT * 16 && o >= OREAL) continue;
    float bb = bias ? bias[o] : 0.f;
#pragma unroll
    for (int r = 0; r < 4; r++) {
      int row = (wv << 4) + ((lane >> 4) << 2) + r;
      int hh = h0 + (row >> 3), ww = w0 + (row & 7);
      y[((size_t)(b * OREAL + o)) * kHW + hh * kW + ww] = acc[nt][r] + bb;
    }
  }
}

// ---------------- BN stats (one block per channel) ----------------
__global__ __launch_bounds__(256) void bn_stats(const float* __restrict__ y,
                                                const float* __restrict__ g,
                                                const float* __restrict__ be,
                                                float* __restrict__ ss, int C) {
  const int c = blockIdx.x;
  float s = 0.f, s2 = 0.f;
  for (int b = 0; b < kB; b++) {
    const float4* p = (const float4*)(y + ((size_t)(b * C + c)) * kHW);
    for (int i = threadIdx.x; i < kHW / 4; i += 256) {
      float4 v = p[i];
      s += v.x + v.y + v.z + v.w;
      s2 += v.x * v.x + v.y * v.y + v.z * v.z + v.w * v.w;
    }
  }
#pragma unroll
  for (int o = 32; o > 0; o >>= 1) {
    s += __shfl_down(s, o, 64);
    s2 += __shfl_down(s2, o, 64);
  }
  __shared__ float red[8];
  int lane = threadIdx.x & 63, wid = threadIdx.x >> 6;
  if (lane == 0) {
    red[wid] = s;
    red[4 + wid] = s2;
  }
  __syncthreads();
  if (threadIdx.x == 0) {
    float S = red[0] + red[1] + red[2] + red[3];
    float S2 = red[4] + red[5] + red[6] + red[7];
    const float inv = 1.f / (float)(kB * kHW);
    float mu = S * inv;
    float var = S2 * inv - mu * mu;
    float sc = g[c] * rsqrtf(var + 1e-5f);
    ss[2 * c] = sc;
    ss[2 * c + 1] = be[c] - mu * sc;
  }
}

// ---------------- BN apply + ReLU (final, NCHW in-place) ----------------
__global__ __launch_bounds__(256) void bn_apply(const float* __restrict__ y,
                                                const float* __restrict__ ss,
                                                float* __restrict__ out, int C,
                                                int total4) {
  int idx = blockIdx.x * 256 + threadIdx.x;
  int stride = gridDim.x * 256;
  for (int i = idx; i < total4; i += stride) {
    int c = (i >> 12) % C;
    float sc = ss[2 * c], shf = ss[2 * c + 1];
    float4 v = ((const float4*)y)[i];
    v.x = fmaxf(fmaf(v.x, sc, shf), 0.f);
    v.y = fmaxf(fmaf(v.y, sc, shf), 0.f);
    v.z = fmaxf(fmaf(v.z, sc, shf), 0.f);
    v.w = fmaxf(fmaf(v.w, sc, shf), 0.f);
    ((float4*)out)[i] = v;
  }
}

// ---------------- launch ----------------
extern "C" void kernel_launch(void* const* d_in, const int* in_sizes, int n_in,
                              void* d_out, int out_size, void* d_ws, size_t ws_size,
                              hipStream_t stream) {
  const float* x      = (const float*)d_in[0];
  const float* w_off1 = (const float*)d_in[1];
  const float* b_off1 = (const float*)d_in[2];
  const float* w1     = (const float*)d_in[3];
  const float* b1     = (const float*)d_in[4];
  const float* g1     = (const float*)d_in[5];
  const float* be1    = (const float*)d_in[6];
  const float* w_off2 = (const float*)d_in[7];
  const float* b_off2 = (const float*)d_in[8];
  const float* w2     = (const float*)d_in[9];
  const float* b2     = (const float*)d_in[10];
  const float* g2     = (const float*)d_in[11];
  const float* be2    = (const float*)d_in[12];

  char* ws = (char*)d_ws;
  const size_t XT_OFF  = 0;                        // xt1 (33.5MB); xt2 aliases
  const size_t XT_SZ   = (size_t)kB * kHW * kC1 * 2;
  const size_t OM_OFF  = XT_OFF + XT_SZ;           // 7MB
  const size_t OM_SZ   = (size_t)27 * kB * kHW * 4;
  const size_t BPO1_OFF = OM_OFF + OM_SZ;          // 147KB
  const size_t BPO1_SZ  = (size_t)9 * (kC1 / 32) * 2 * 512 * 2;
  const size_t BP1_OFF = BPO1_OFF + BPO1_SZ;       // 590KB
  const size_t BP1_SZ  = (size_t)9 * (kC1 / 32) * (kM / 16) * 512 * 2;
  const size_t BPO2_OFF = BP1_OFF + BP1_SZ;        // 74KB
  const size_t BPO2_SZ  = (size_t)9 * (kM / 32) * 2 * 512 * 2;
  const size_t BP2_OFF = BPO2_OFF + BPO2_SZ;       // 1.18MB
  const size_t BP2_SZ  = (size_t)9 * (kM / 32) * (kC2 / 16) * 512 * 2;
  const size_t SS_OFF  = BP2_OFF + BP2_SZ;

  u16* xt1  = (u16*)(ws + XT_OFF);
  u16* xt2  = (u16*)(ws + XT_OFF);  // alias: xt1 dead before xt2 written
  float* om = (float*)(ws + OM_OFF);
  u16* bpo1 = (u16*)(ws + BPO1_OFF);
  u16* bp1  = (u16*)(ws + BP1_OFF);
  u16* bpo2 = (u16*)(ws + BPO2_OFF);
  u16* bp2  = (u16*)(ws + BP2_OFF);
  float* ssb = (float*)(ws + SS_OFF);
  float* y1 = (float*)d_out;
  float* y2 = (float*)d_out;

  // ---------- layer 1 ----------
  to_nhwc<false><<<256, 256, 0, stream>>>(x, nullptr, xt1, kC1);
  prep_bpack<<<(9 * 8 * 2 * 512 + 255) / 256, 256, 0, stream>>>(w_off1, bpo1, kC1, 2, 27);
  prep_bpack<<<(9 * 8 * 8 * 512 + 255) / 256, 256, 0, stream>>>(w1, bp1, kC1, 8, kM);
  dcn_mfma<kC1, 2, 2, 27, false><<<dim3(256, kB, 1), 256, 0, stream>>>(
      xt1, nullptr, nullptr, bpo1, nullptr, om);
  dcn_mfma<kC1, 8, 8, kM, true><<<dim3(256, kB, 1), 256, 0, stream>>>(
      xt1, om, b_off1, bp1, b1, y1);
  bn_stats<<<kM, 256, 0, stream>>>(y1, g1, be1, ssb, kM);
  to_nhwc<true><<<256, 256, 0, stream>>>(y1, ssb, xt2, kM);

  // ---------- layer 2 ----------
  prep_bpack<<<(9 * 4 * 2 * 512 + 255) / 256, 256, 0, stream>>>(w_off2, bpo2, kM, 2, 27);
  prep_bpack<<<(9 * 4 * 16 * 512 + 255) / 256, 256, 0, stream>>>(w2, bp2, kM, 16, kC2);
  dcn_mfma<kM, 2, 2, 27, false><<<dim3(256, kB, 1), 256, 0, stream>>>(
      xt2, nullptr, nullptr, bpo2, nullptr, om);
  dcn_mfma<kM, 16, 8, kC2, true><<<dim3(256, kB, 2), 256, 0, stream>>>(
      xt2, om, b_off2, bp2, b2, y2);
  bn_stats<<<kC2, 256, 0, stream>>>(y2, g2, be2, ssb, kC2);
  bn_apply<<<2048, 256, 0, stream>>>(y2, ssb, (float*)d_out, kC2, kB * kC2 * kHW / 4);
}